// Round 1
// baseline (6670.098 us; speedup 1.0000x reference)
//
#include <hip/hip_runtime.h>
#include <hip/hip_cooperative_groups.h>

namespace cg = cooperative_groups;

// Problem constants (from reference setup_inputs)
constexpr int B = 4;
constexpr int T = 96;
constexpr int N = 512;        // also softmax width
constexpr int PW = 2 + N;     // 514 params per row
constexpr float EPS_F = 1e-8f;

// One wave (64 lanes) per (b, n) row. 2048 rows -> 512 blocks x 256 threads.
// Persistent cooperative kernel: 96 time steps, grid.sync() between steps.
// Double-buffered I-vector lives in d_ws (2 * B * N floats).

__global__ __launch_bounds__(256, 2)
void ssir_fused(const float* __restrict__ x0,
                const float* __restrict__ params,
                float* __restrict__ out,
                float* __restrict__ ws)
{
    cg::grid_group grid = cg::this_grid();

    const int tid  = blockIdx.x * blockDim.x + threadIdx.x;
    const int wave = tid >> 6;          // 0 .. B*N-1
    const int lane = tid & 63;
    const int b    = wave >> 9;         // wave / N
    const int n    = wave & (N - 1);    // wave % N

    float* Ibuf0 = ws;            // [B*N]
    float* Ibuf1 = ws + B * N;    // [B*N]

    // ---- init state from x0 ----
    const float* x0r = x0 + (size_t)(b * N + n) * 3;
    float S = x0r[0];
    float I = x0r[1];
    float R = x0r[2];
    if (lane == 0) Ibuf0[b * N + n] = I;

    float* outx = out;                                  // (B,T,N,3)
    float* epi  = out + (size_t)B * T * N * 3;          // (B,T,N,514)

    const size_t prow0 = ((size_t)(b * T) * N + n) * PW; // row (b, t=0, n)
    const size_t tstride = (size_t)N * PW;               // per-t stride

    // ---- prefetch params for t = 0 ----
    float p[8];
    {
        const float* pr = params + prow0;
        #pragma unroll
        for (int j = 0; j < 8; ++j) p[j] = pr[2 + lane + 64 * j];
    }
    float pb = params[prow0 + 0];
    float pg = params[prow0 + 1];

    for (int t = 0; t < T; ++t) {
        // ---- softmax over 512 logits (8 per lane, stride-64 layout) ----
        float m = p[0];
        #pragma unroll
        for (int j = 1; j < 8; ++j) m = fmaxf(m, p[j]);
        #pragma unroll
        for (int s = 1; s < 64; s <<= 1) m = fmaxf(m, __shfl_xor(m, s, 64));

        float c[8];
        float sum = 0.f;
        #pragma unroll
        for (int j = 0; j < 8; ++j) { c[j] = expf(p[j] - m); sum += c[j]; }
        #pragma unroll
        for (int s = 1; s < 64; s <<= 1) sum += __shfl_xor(sum, s, 64);
        const float inv = 1.0f / sum;
        #pragma unroll
        for (int j = 0; j < 8; ++j) c[j] *= inv;

        const float beta  = 1.0f / (1.0f + expf(-pb));
        const float gamma = 1.0f / (1.0f + expf(-pg));

        // ---- write epiparams row (b,t,n,:) ----
        {
            float* er = epi + ((size_t)((b * T + t) * N) + n) * PW;
            #pragma unroll
            for (int j = 0; j < 8; ++j) er[2 + lane + 64 * j] = c[j];
            if (lane == 0) { er[0] = beta; er[1] = gamma; }
        }

        // ---- prefetch params for t+1 (issue loads before the sync) ----
        float pnext[8], pbn = 0.f, pgn = 0.f;
        if (t + 1 < T) {
            const float* prn = params + prow0 + (size_t)(t + 1) * tstride;
            #pragma unroll
            for (int j = 0; j < 8; ++j) pnext[j] = prn[2 + lane + 64 * j];
            pbn = prn[0];
            pgn = prn[1];
        }

        // ---- sync: guarantees I-vector for this step is fully published ----
        grid.sync();

        // ---- infection = c_row . I  (I in global, L2-broadcast across waves) ----
        const float* Icur = (t & 1) ? Ibuf1 : Ibuf0;
        float*       Inxt = (t & 1) ? Ibuf0 : Ibuf1;

        float dot = 0.f;
        #pragma unroll
        for (int j = 0; j < 8; ++j) dot += c[j] * Icur[b * N + lane + 64 * j];
        #pragma unroll
        for (int s = 1; s < 64; s <<= 1) dot += __shfl_xor(dot, s, 64);

        // ---- SIR state update (all lanes redundantly) ----
        const float Npop  = fmaxf(S + I + R, EPS_F);
        const float dS    = -beta * S / Npop * dot;
        const float dI    = -dS - gamma * I;
        const float dR    = gamma * I;
        const float St    = fmaxf(S + dS, 0.f);
        const float It    = fmaxf(I + dI, 0.f);
        const float Rt    = fmaxf(R + dR, 0.f);
        const float scale = Npop / fmaxf(St + It + Rt, EPS_F);
        S = St * scale;
        I = It * scale;
        R = Rt * scale;

        // ---- write trajectory (b,t,n,0:3) and publish I for next step ----
        if (lane < 3) {
            const float v = (lane == 0) ? S : (lane == 1) ? I : R;
            outx[((size_t)((b * T + t) * N) + n) * 3 + lane] = v;
        }
        if (lane == 0) Inxt[b * N + n] = I;

        // rotate prefetched params
        #pragma unroll
        for (int j = 0; j < 8; ++j) p[j] = pnext[j];
        pb = pbn;
        pg = pgn;
    }
}

extern "C" void kernel_launch(void* const* d_in, const int* in_sizes, int n_in,
                              void* d_out, int out_size, void* d_ws, size_t ws_size,
                              hipStream_t stream) {
    const float* x0     = (const float*)d_in[0];
    const float* params = (const float*)d_in[1];
    float* outp = (float*)d_out;
    float* wsp  = (float*)d_ws;

    void* args[] = { (void*)&x0, (void*)&params, (void*)&outp, (void*)&wsp };
    hipLaunchCooperativeKernel((void*)ssir_fused,
                               dim3((B * N) / 4),   // 512 blocks
                               dim3(256),           // 4 waves/block, 1 wave per row
                               args, 0, stream);
}